// Round 6
// baseline (235.279 us; speedup 1.0000x reference)
//
#include <hip/hip_runtime.h>
#include <hip/hip_bf16.h>
#include <math.h>

#define B 4
#define C 64
#define H 128
#define W 128
#define KK 9
#define CENTER 4
#define HW (H*W)         // 16384
#define HP 130           // padded height
#define WP 130           // padded width

typedef __attribute__((ext_vector_type(8))) short short8;   // 8 x bf16 (4 VGPRs)
typedef __attribute__((ext_vector_type(4))) float f4;       // MFMA C/D frag

// ---------------- workspace layout (in floats) ----------------
#define OFF_OFFT   0                       // offT: B*H*W*16 = 1048576
#define OFF_XB     1048576                 // xb: B*130*130*64 bf16 = 2163200 floats
#define OFF_WB     3211776                 // wb: KK*C*C bf16 = 18432 floats
#define OFF_WOB    3230208                 // wob: 9*16*64 bf16 = 4608 floats
#define OFF_CSUM   3234816                 // B*C*2 = 512 (zeroed by k_prep)
#define OFF_OSUM   3235328                 // 64 (zeroed by k_prep, contiguous w/ csum)
// total 3235392 floats = 12.94 MB

__device__ __forceinline__ unsigned bf16pack(float a, float b) {
    // round-half-up to bf16; a->low16, b->high16
    unsigned ua = __builtin_bit_cast(unsigned, a) + 0x8000u;
    unsigned ub = __builtin_bit_cast(unsigned, b) + 0x8000u;
    return __builtin_amdgcn_perm(ub, ua, 0x07060302);
}

__device__ __forceinline__ unsigned lerp_pack(unsigned a, unsigned b, float fw) {
    // a,b each hold 2 bf16 (lo,hi); y-lerp both, repack
    float alo = __builtin_bit_cast(float, a << 16);
    float ahi = __builtin_bit_cast(float, a & 0xffff0000u);
    float blo = __builtin_bit_cast(float, b << 16);
    float bhi = __builtin_bit_cast(float, b & 0xffff0000u);
    float slo = alo + fw * (blo - alo);
    float shi = ahi + fw * (bhi - ahi);
    return bf16pack(slo, shi);
}

__device__ __forceinline__ float fast_tanh(float x) {
    float e = __expf(2.f * x);
    return 1.f - 2.f * __builtin_amdgcn_rcpf(e + 1.f);
}

// ---- K0 (k_prep): fused input transpose + weight converts + accum zeroing ----
// blocks 0..511   : x [b][ci][h][w] fp32 -> xb [b][hp][wp][ci] bf16 (interior)
// blocks 512..519 : zero border rows hp=0,129
// blocks 520..699 : w_dsc -> wb [k][co][ci] bf16 ; w_off -> wob [tap][j16][ci] bf16
// block  700      : zero csum(512)+osum(64)
__global__ __launch_bounds__(256) void k_prep(const float* __restrict__ x,
                                              const float* __restrict__ w_dsc,
                                              const float* __restrict__ w_off,
                                              unsigned short* __restrict__ xb,
                                              unsigned short* __restrict__ wb,
                                              unsigned short* __restrict__ wob,
                                              float* __restrict__ csum) {
    int bid = blockIdx.x;
    int tid = threadIdx.x;
    if (bid < B * H) {
        __shared__ float lt[64 * 33];
        int b = bid >> 7, h = bid & 127;
        int ciA = tid >> 2, gA = tid & 3;          // phase A roles
        int wlB = tid >> 3, cgB = tid & 7;         // phase B roles

        // zero cols wp=0,129 of this row
        if (tid < 16) {
            int which = tid >> 3, q = tid & 7;
            *(uint4*)(xb + (((size_t)(b * HP + h + 1) * WP) + which * (WP - 1)) * 64 + q * 8)
                = make_uint4(0, 0, 0, 0);
        }
        for (int c = 0; c < 4; c++) {
            int w0 = c * 32;
            __syncthreads();
            {
                const float* src = x + ((size_t)(b * C + ciA) * HW) + h * W + w0 + gA * 8;
                float4 v0 = *(const float4*)src;
                float4 v1 = *(const float4*)(src + 4);
                float* d = lt + ciA * 33 + gA * 8;
                d[0] = v0.x; d[1] = v0.y; d[2] = v0.z; d[3] = v0.w;
                d[4] = v1.x; d[5] = v1.y; d[6] = v1.z; d[7] = v1.w;
            }
            __syncthreads();
            {
                unsigned u[4];
#pragma unroll
                for (int i = 0; i < 4; i++) {
                    float lo = lt[(cgB * 8 + 2 * i)     * 33 + wlB];
                    float hi = lt[(cgB * 8 + 2 * i + 1) * 33 + wlB];
                    u[i] = bf16pack(lo, hi);
                }
                *(uint4*)(xb + ((size_t)((b * HP + h + 1) * WP + w0 + wlB + 1)) * 64 + cgB * 8) =
                    make_uint4(u[0], u[1], u[2], u[3]);
            }
        }
    } else if (bid < B * H + 8) {
        int r = bid - B * H;
        int b = r >> 1, which = r & 1;
        unsigned short* dst = xb + ((size_t)(b * HP + which * (HP - 1)) * WP) * 64;
        for (int t = tid; t < WP * 64 / 8; t += 256)
            *(uint4*)(dst + t * 8) = make_uint4(0, 0, 0, 0);
    } else if (bid < B * H + 8 + 180) {
        int idx = (bid - (B * H + 8)) * 256 + tid;
        if (idx < KK * C * C) {
            int k  = idx >> 12;
            int r  = idx & 4095;
            int co = r >> 6;
            int ci = r & 63;
            unsigned u = __builtin_bit_cast(unsigned, w_dsc[(co * C + ci) * KK + k]);
            u = (u + 0x7fffu + ((u >> 16) & 1u)) >> 16;
            wb[idx] = (unsigned short)u;
        } else if (idx < KK * C * C + 9 * 16 * 64) {
            int r   = idx - KK * C * C;
            int tap = r >> 10;
            int j   = (r >> 6) & 15;
            int ci  = r & 63;
            float v = (j < 10) ? w_off[(j * C + ci) * 9 + tap] : 0.f;
            unsigned u = __builtin_bit_cast(unsigned, v);
            u = (u + 0x7fffu + ((u >> 16) & 1u)) >> 16;
            wob[r] = (unsigned short)u;
        }
    } else {
        if (tid < 576) csum[tid] = 0.f;    // csum(512) + osum(64) contiguous
    }
}

// ---- K1: offset conv via MFMA, barrier-free K-loop. Wave = one 16-pixel tile.
// Stores offT [b][h][w][16] (j in low 10) + GN raw sums.
__global__ __launch_bounds__(256, 8) void k_offconv(const unsigned short* __restrict__ xb,
                                                    const unsigned short* __restrict__ wob,
                                                    const float* __restrict__ b_off,
                                                    float* __restrict__ offT,
                                                    float* __restrict__ osum) {
    __shared__ float red[80];
    int bid = blockIdx.x;          // 1024: xcd(8) x [b(4) x hc(16) x half(2)]
    int xcd  = bid & 7;
    int i    = bid >> 3;
    int b    = i >> 5;
    int rest = i & 31;
    int h    = (xcd << 4) | (rest >> 1);
    int half = rest & 1;
    int tid  = threadIdx.x;
    int wid  = tid >> 6;
    int lane = tid & 63;
    int lm = lane & 15, qd = lane >> 4;
    int pw = half * 64 + wid * 16;           // tile base pixel

    f4 acc = 0;
    const unsigned short* xrow = xb + ((size_t)(b * HP + h) * WP) * 64;  // hp = h+ky
#pragma unroll
    for (int ky = 0; ky < 3; ky++)
#pragma unroll
        for (int kx = 0; kx < 3; kx++) {
            int tap = ky * 3 + kx;
            int wp = pw + lm + kx;           // padded col index
#pragma unroll
            for (int s = 0; s < 2; s++) {
                short8 bfr = *(const short8*)(wob + (tap * 16 + lm) * 64 + s * 32 + qd * 8);
                short8 afr = *(const short8*)(xrow +
                    ((size_t)(ky * WP + wp)) * 64 + s * 32 + qd * 8);
                acc = __builtin_amdgcn_mfma_f32_16x16x32_bf16(afr, bfr, acc, 0, 0, 0);
            }
        }

    // epilogue: +bias, store offT[p][j], GN raw partial sums (j<10)
    float bo = b_off[lm];
    float sv = 0.f, sq = 0.f;
#pragma unroll
    for (int r = 0; r < 4; r++) {
        float val = acc[r] + bo;
        int p = pw + qd * 4 + r;
        offT[((size_t)((b * H + h) * W + p)) * 16 + lm] = val;
        if (lm < 10) { sv += val; sq += val * val; }
    }
    sv += __shfl_xor(sv, 16); sv += __shfl_xor(sv, 32);
    sq += __shfl_xor(sq, 16); sq += __shfl_xor(sq, 32);
    if (lane < 16 && lm < 10) {
        red[(wid * 10 + lm) * 2]     = sv;
        red[(wid * 10 + lm) * 2 + 1] = sq;
    }
    __syncthreads();
    if (tid < 20) {
        int j = tid >> 1, comp = tid & 1;
        float s = red[j * 2 + comp] + red[(10 + j) * 2 + comp] +
                  red[(20 + j) * 2 + comp] + red[(30 + j) * 2 + comp];
        atomicAdd(&osum[(b * 5 + (j >> 1)) * 2 + comp], s);
    }
}

// ---- K2: fused tanh+cumsum+resample + MFMA 9x1 conv, co-split x2 ----
// Block = (b,h,half,cohalf): 64 pixels x 32 co. 2048 blocks = 8/CU.
__global__ __launch_bounds__(256, 8) void k_main(const unsigned short* __restrict__ xb,
                                                 const float* __restrict__ offT,
                                                 const float* __restrict__ osum,
                                                 const float* __restrict__ g_gn_off,
                                                 const float* __restrict__ b_gn_off,
                                                 const unsigned short* __restrict__ wb,
                                                 const float* __restrict__ b_dsc,
                                                 float* __restrict__ outp,
                                                 float* __restrict__ csum) {
    __shared__ float red[256];     // [wid][ct][lm][2]

    int bid = blockIdx.x;          // 2048: xcd(8) x [b(4) x hc(16) x half(2) x coh(2)]
    int xcd  = bid & 7;
    int i    = bid >> 3;
    int b    = i >> 6;
    int rest = i & 63;
    int h    = (xcd << 4) | (rest >> 2);
    int p0   = ((rest >> 1) & 1) << 6;
    int co0  = (rest & 1) << 5;
    int tid  = threadIdx.x;
    int wid  = tid >> 6;
    int lane = tid & 63;
    int lm = lane & 15, qd = lane >> 4;

    int ps = p0 + wid * 16 + lm;   // this thread's pixel (dup x4 across quads)

    // ---- offset GN stats ----
    float means[5], rstds[5];
    const float inv_n = 1.f / (2.f * HW);
#pragma unroll
    for (int g = 0; g < 5; g++) {
        float s  = osum[(b * 5 + g) * 2];
        float s2 = osum[(b * 5 + g) * 2 + 1];
        float mean = s * inv_n;
        float var  = s2 * inv_n - mean * mean;
        means[g] = mean;
        rstds[g] = rsqrtf(var + 1e-5f);
    }

    // ---- offsets (pixel-contiguous) -> sampling coords ----
    int   ofsA[KK], ofsB[KK];
    float wya[KK];
    {
        const float* op = offT + ((size_t)((b * H + h) * W + ps)) * 16;
        f4 o0 = *(const f4*)op;
        f4 o1 = *(const f4*)(op + 4);
        float o8 = op[8];
        float raw[KK] = {o0[0], o0[1], o0[2], o0[3], o1[0], o1[1], o1[2], o1[3], o8};
        float v[KK];
#pragma unroll
        for (int j = 0; j < KK; j++) {
            int g = j >> 1;
            v[j] = fast_tanh((raw[j] - means[g]) * rstds[g] * g_gn_off[j] + b_gn_off[j]);
        }
        float yoff[KK];
        yoff[CENTER] = 0.f;
        float run = 0.f;
#pragma unroll
        for (int k = CENTER - 1; k >= 0; k--) { run += v[k]; yoff[k] = run; }
        run = 0.f;
#pragma unroll
        for (int k = CENTER + 1; k < KK; k++) { run += v[k]; yoff[k] = run; }
#pragma unroll
        for (int k = 0; k < KK; k++) {
            float yc = fminf(fmaxf((float)h + yoff[k], 0.f), (float)(H - 1));
            float fy = floorf(yc);
            int y0 = (int)fy;
            int y1 = min(y0 + 1, H - 1);
            wya[k] = yc - fy;
            int xi = min(max(ps + k - CENTER, 0), W - 1);
            ofsA[k] = ((b * HP + y0 + 1) * WP + xi + 1) * 64;
            ofsB[k] = ((b * HP + y1 + 1) * WP + xi + 1) * 64;
        }
    }

    f4 acc[2];
    acc[0] = 0; acc[1] = 0;

#pragma unroll
    for (int k = 0; k < KK; k++) {
        const unsigned short* wk = wb + k * (C * C) + co0 * 64;
        float fw = wya[k];
#pragma unroll
        for (int s = 0; s < 2; s++) {
            int co_ofs = s * 32 + qd * 8;
            uint4 a  = *(const uint4*)(xb + ofsA[k] + co_ofs);
            uint4 bb = *(const uint4*)(xb + ofsB[k] + co_ofs);
            uint4 r;
            r.x = lerp_pack(a.x, bb.x, fw);
            r.y = lerp_pack(a.y, bb.y, fw);
            r.z = lerp_pack(a.z, bb.z, fw);
            r.w = lerp_pack(a.w, bb.w, fw);
            short8 afr = __builtin_bit_cast(short8, r);
#pragma unroll
            for (int ct = 0; ct < 2; ct++) {
                short8 bfr = *(const short8*)(wk + (ct * 16 + lm) * 64 + co_ofs);
                acc[ct] = __builtin_amdgcn_mfma_f32_16x16x32_bf16(afr, bfr,
                                                                  acc[ct], 0, 0, 0);
            }
        }
    }

    // ---- epilogue: +bias, direct f4 stores, GN partials ----
#pragma unroll
    for (int ct = 0; ct < 2; ct++) {
        int co = co0 + ct * 16 + lm;
        float bias = b_dsc[co];
        f4 v;
        float sv = 0.f, sq = 0.f;
#pragma unroll
        for (int r = 0; r < 4; r++) {
            v[r] = acc[ct][r] + bias;
            sv += v[r]; sq += v[r] * v[r];
        }
        *(f4*)(outp + ((size_t)(b * C + co)) * HW + h * W + p0 + wid * 16 + qd * 4) = v;
        sv += __shfl_xor(sv, 16); sv += __shfl_xor(sv, 32);
        sq += __shfl_xor(sq, 16); sq += __shfl_xor(sq, 32);
        if (lane < 16) {
            red[((wid * 2 + ct) * 16 + lm) * 2]     = sv;
            red[((wid * 2 + ct) * 16 + lm) * 2 + 1] = sq;
        }
    }
    __syncthreads();
    if (tid < 64) {
        int col = tid >> 1, comp = tid & 1;      // col 0..31 within co0 half
        int ct = col >> 4, lmr = col & 15;
        float s = 0.f;
#pragma unroll
        for (int w2 = 0; w2 < 4; w2++)
            s += red[((w2 * 2 + ct) * 16 + lmr) * 2 + comp];
        atomicAdd(&csum[(b * C + co0 + col) * 2 + comp], s);
    }
}

// ---- K3: GN finalize (per block) + apply + ReLU ----
__global__ __launch_bounds__(256) void k_norm(float* __restrict__ outp,
                                              const float* __restrict__ csum,
                                              const float* __restrict__ g_gn,
                                              const float* __restrict__ b_gn) {
    int bid = blockIdx.x;           // 4096: bc(256) x 16
    int bc = bid >> 4;
    int b = bc >> 6, co = bc & 63;
    int grp = co >> 2;
    float S = 0.f, S2 = 0.f;
#pragma unroll
    for (int c2 = 0; c2 < 4; c2++) {
        S  += csum[(b * C + grp * 4 + c2) * 2];
        S2 += csum[(b * C + grp * 4 + c2) * 2 + 1];
    }
    float n = 4.f * HW;
    float mean = S / n;
    float var  = S2 / n - mean * mean;
    float rstd = rsqrtf(var + 1e-5f);
    float sc = rstd * g_gn[co];
    float sh = b_gn[co] - mean * sc;

    int idx = bid * 256 + threadIdx.x;
    float4* ptr = (float4*)outp;
    float4 vv = ptr[idx];
    vv.x = fmaxf(vv.x * sc + sh, 0.f);
    vv.y = fmaxf(vv.y * sc + sh, 0.f);
    vv.z = fmaxf(vv.z * sc + sh, 0.f);
    vv.w = fmaxf(vv.w * sc + sh, 0.f);
    ptr[idx] = vv;
}

extern "C" void kernel_launch(void* const* d_in, const int* in_sizes, int n_in,
                              void* d_out, int out_size, void* d_ws, size_t ws_size,
                              hipStream_t stream) {
    const float* x        = (const float*)d_in[0];
    const float* w_off    = (const float*)d_in[1];
    const float* b_off    = (const float*)d_in[2];
    const float* g_gn_off = (const float*)d_in[3];
    const float* b_gn_off = (const float*)d_in[4];
    const float* w_dsc    = (const float*)d_in[5];
    const float* b_dsc    = (const float*)d_in[6];
    const float* g_gn     = (const float*)d_in[7];
    const float* b_gn     = (const float*)d_in[8];
    float* out = (float*)d_out;
    float* ws  = (float*)d_ws;

    float*          offT = ws + OFF_OFFT;
    unsigned short* xbp  = (unsigned short*)(ws + OFF_XB);
    unsigned short* wbp  = (unsigned short*)(ws + OFF_WB);
    unsigned short* wobp = (unsigned short*)(ws + OFF_WOB);
    float*          csum = ws + OFF_CSUM;
    float*          osum = ws + OFF_OSUM;

    k_prep<<<B * H + 8 + 180 + 1, 256, 0, stream>>>(x, w_dsc, w_off, xbp, wbp,
                                                    wobp, csum);
    k_offconv<<<2 * B * H, 256, 0, stream>>>(xbp, wobp, b_off, offT, osum);
    k_main<<<4 * B * H, 256, 0, stream>>>(xbp, offT, osum, g_gn_off, b_gn_off,
                                          wbp, b_dsc, out, csum);
    k_norm<<<B * C * HW / 4 / 256, 256, 0, stream>>>(out, csum, g_gn, b_gn);
}

// Round 7
// 224.286 us; speedup vs baseline: 1.0490x; 1.0490x over previous
//
#include <hip/hip_runtime.h>
#include <hip/hip_bf16.h>
#include <math.h>

#define B 4
#define C 64
#define H 128
#define W 128
#define KK 9
#define CENTER 4
#define HW (H*W)         // 16384
#define HP 130           // padded height
#define WP 130           // padded width

typedef __attribute__((ext_vector_type(8))) short short8;   // 8 x bf16 (4 VGPRs)
typedef __attribute__((ext_vector_type(4))) float f4;       // MFMA C/D frag

// ---------------- workspace layout (in floats) ----------------
#define OFF_OFFT   0                       // offT: B*H*W*16 = 1048576
#define OFF_XB     1048576                 // xb: B*130*130*64 bf16 = 2163200 floats
#define OFF_WB     3211776                 // wb: KK*C*C bf16 = 18432 floats
#define OFF_WOB    3230208                 // wob: 9*16*64 bf16 = 4608 floats
#define OFF_CSUM   3234816                 // B*C*2 = 512 (zeroed by k_prep)
#define OFF_OSUM   3235328                 // 64 (zeroed by k_prep, contiguous w/ csum)
// total 3235392 floats = 12.94 MB

__device__ __forceinline__ unsigned bf16pack(float a, float b) {
    // round-half-up to bf16; a->low16, b->high16
    unsigned ua = __builtin_bit_cast(unsigned, a) + 0x8000u;
    unsigned ub = __builtin_bit_cast(unsigned, b) + 0x8000u;
    return __builtin_amdgcn_perm(ub, ua, 0x07060302);
}

__device__ __forceinline__ unsigned lerp_pack(unsigned a, unsigned b, float fw) {
    // a,b each hold 2 bf16 (lo,hi); y-lerp both, repack
    float alo = __builtin_bit_cast(float, a << 16);
    float ahi = __builtin_bit_cast(float, a & 0xffff0000u);
    float blo = __builtin_bit_cast(float, b << 16);
    float bhi = __builtin_bit_cast(float, b & 0xffff0000u);
    float slo = alo + fw * (blo - alo);
    float shi = ahi + fw * (bhi - ahi);
    return bf16pack(slo, shi);
}

__device__ __forceinline__ float fast_tanh(float x) {
    float e = __expf(2.f * x);
    return 1.f - 2.f * __builtin_amdgcn_rcpf(e + 1.f);
}

// ---- K0 (k_prep): fused input transpose + weight converts + accum zeroing ----
// blocks 0..2047       : x[b][ci][h][w0..w0+31] fp32 -> xb[b][hp][wp][ci] bf16
// blocks 2048..2055    : zero border rows hp=0,129
// blocks 2056..2235    : w_dsc -> wb [k][co][ci] ; w_off -> wob [tap][j16][ci]
// block  2236          : zero csum(512)+osum(64)
__global__ __launch_bounds__(256) void k_prep(const float* __restrict__ x,
                                              const float* __restrict__ w_dsc,
                                              const float* __restrict__ w_off,
                                              unsigned short* __restrict__ xb,
                                              unsigned short* __restrict__ wb,
                                              unsigned short* __restrict__ wob,
                                              float* __restrict__ csum) {
    int bid = blockIdx.x;
    int tid = threadIdx.x;
    if (bid < 4 * B * H) {
        __shared__ float lt[64 * 33];
        int b = bid >> 9;
        int h = (bid >> 2) & 127;
        int c = bid & 3;
        int w0 = c * 32;
        int ciA = tid >> 2, gA = tid & 3;          // phase A roles
        int wlB = tid >> 3, cgB = tid & 7;         // phase B roles

        // zero cols wp=0 (c==0) / wp=129 (c==3) of this row
        if (c == 0 && tid < 8)
            *(uint4*)(xb + ((size_t)(b * HP + h + 1) * WP) * 64 + tid * 8)
                = make_uint4(0, 0, 0, 0);
        if (c == 3 && tid < 8)
            *(uint4*)(xb + (((size_t)(b * HP + h + 1) * WP) + WP - 1) * 64 + tid * 8)
                = make_uint4(0, 0, 0, 0);
        {
            const float* src = x + ((size_t)(b * C + ciA) * HW) + h * W + w0 + gA * 8;
            float4 v0 = *(const float4*)src;
            float4 v1 = *(const float4*)(src + 4);
            float* d = lt + ciA * 33 + gA * 8;
            d[0] = v0.x; d[1] = v0.y; d[2] = v0.z; d[3] = v0.w;
            d[4] = v1.x; d[5] = v1.y; d[6] = v1.z; d[7] = v1.w;
        }
        __syncthreads();
        {
            unsigned u[4];
#pragma unroll
            for (int i = 0; i < 4; i++) {
                float lo = lt[(cgB * 8 + 2 * i)     * 33 + wlB];
                float hi = lt[(cgB * 8 + 2 * i + 1) * 33 + wlB];
                u[i] = bf16pack(lo, hi);
            }
            *(uint4*)(xb + ((size_t)((b * HP + h + 1) * WP + w0 + wlB + 1)) * 64 + cgB * 8) =
                make_uint4(u[0], u[1], u[2], u[3]);
        }
    } else if (bid < 4 * B * H + 8) {
        int r = bid - 4 * B * H;
        int b = r >> 1, which = r & 1;
        unsigned short* dst = xb + ((size_t)(b * HP + which * (HP - 1)) * WP) * 64;
        for (int t = tid; t < WP * 64 / 8; t += 256)
            *(uint4*)(dst + t * 8) = make_uint4(0, 0, 0, 0);
    } else if (bid < 4 * B * H + 8 + 180) {
        int idx = (bid - (4 * B * H + 8)) * 256 + tid;
        if (idx < KK * C * C) {
            int k  = idx >> 12;
            int r  = idx & 4095;
            int co = r >> 6;
            int ci = r & 63;
            unsigned u = __builtin_bit_cast(unsigned, w_dsc[(co * C + ci) * KK + k]);
            u = (u + 0x7fffu + ((u >> 16) & 1u)) >> 16;
            wb[idx] = (unsigned short)u;
        } else if (idx < KK * C * C + 9 * 16 * 64) {
            int r   = idx - KK * C * C;
            int tap = r >> 10;
            int j   = (r >> 6) & 15;
            int ci  = r & 63;
            float v = (j < 10) ? w_off[(j * C + ci) * 9 + tap] : 0.f;
            unsigned u = __builtin_bit_cast(unsigned, v);
            u = (u + 0x7fffu + ((u >> 16) & 1u)) >> 16;
            wob[r] = (unsigned short)u;
        }
    } else {
        if (tid < 576) csum[tid] = 0.f;    // csum(512) + osum(64) contiguous
    }
}

// ---- K1: offset conv via MFMA, batched loads. Wave = one 16-pixel tile. ----
__global__ __launch_bounds__(256, 4) void k_offconv(const unsigned short* __restrict__ xb,
                                                    const unsigned short* __restrict__ wob,
                                                    const float* __restrict__ b_off,
                                                    float* __restrict__ offT,
                                                    float* __restrict__ osum) {
    __shared__ float red[80];
    int bid = blockIdx.x;          // 1024: xcd(8) x [b(4) x hc(16) x half(2)]
    int xcd  = bid & 7;
    int i    = bid >> 3;
    int b    = i >> 5;
    int rest = i & 31;
    int h    = (xcd << 4) | (rest >> 1);
    int half = rest & 1;
    int tid  = threadIdx.x;
    int wid  = tid >> 6;
    int lane = tid & 63;
    int lm = lane & 15, qd = lane >> 4;
    int pw = half * 64 + wid * 16;           // tile base pixel

    f4 acc = 0;
    const unsigned short* xrow = xb + ((size_t)(b * HP + h) * WP) * 64;  // hp = h+ky
#pragma unroll
    for (int s = 0; s < 2; s++) {
        int co_ofs = s * 32 + qd * 8;
        short8 a_[9];
#pragma unroll
        for (int t = 0; t < 9; t++) {
            int ky = t / 3, kx = t - 3 * (t / 3);
            a_[t] = *(const short8*)(xrow +
                ((size_t)(ky * WP + pw + lm + kx)) * 64 + co_ofs);
        }
#pragma unroll
        for (int t = 0; t < 9; t++) {
            short8 bfr = *(const short8*)(wob + (t * 16 + lm) * 64 + co_ofs);
            acc = __builtin_amdgcn_mfma_f32_16x16x32_bf16(a_[t], bfr, acc, 0, 0, 0);
        }
    }

    // epilogue: +bias, store offT[p][j], GN raw partial sums (j<10)
    float bo = b_off[lm];
    float sv = 0.f, sq = 0.f;
#pragma unroll
    for (int r = 0; r < 4; r++) {
        float val = acc[r] + bo;
        int p = pw + qd * 4 + r;
        offT[((size_t)((b * H + h) * W + p)) * 16 + lm] = val;
        if (lm < 10) { sv += val; sq += val * val; }
    }
    sv += __shfl_xor(sv, 16); sv += __shfl_xor(sv, 32);
    sq += __shfl_xor(sq, 16); sq += __shfl_xor(sq, 32);
    if (lane < 16 && lm < 10) {
        red[(wid * 10 + lm) * 2]     = sv;
        red[(wid * 10 + lm) * 2 + 1] = sq;
    }
    __syncthreads();
    if (tid < 20) {
        int j = tid >> 1, comp = tid & 1;
        float s = red[j * 2 + comp] + red[(10 + j) * 2 + comp] +
                  red[(20 + j) * 2 + comp] + red[(30 + j) * 2 + comp];
        atomicAdd(&osum[(b * 5 + (j >> 1)) * 2 + comp], s);
    }
}

// ---- K2: fused tanh+cumsum+resample + MFMA 9x1 conv, batched gathers ----
// Block = (b,h,half): 64 pixels x 64 co. 1024 blocks. 4 phases of 9-10 gathers.
__global__ __launch_bounds__(256, 4) void k_main(const unsigned short* __restrict__ xb,
                                                 const float* __restrict__ offT,
                                                 const float* __restrict__ osum,
                                                 const float* __restrict__ g_gn_off,
                                                 const float* __restrict__ b_gn_off,
                                                 const unsigned short* __restrict__ wb,
                                                 const float* __restrict__ b_dsc,
                                                 float* __restrict__ outp,
                                                 float* __restrict__ csum) {
    __shared__ float red[512];     // [wid][ct][lm][2]

    int bid = blockIdx.x;          // 1024: xcd(8) x [b(4) x hc(16) x half(2)]
    int xcd  = bid & 7;
    int i    = bid >> 3;
    int b    = i >> 5;
    int rest = i & 31;
    int h    = (xcd << 4) | (rest >> 1);
    int p0   = (rest & 1) << 6;
    int tid  = threadIdx.x;
    int wid  = tid >> 6;
    int lane = tid & 63;
    int lm = lane & 15, qd = lane >> 4;

    int ps = p0 + wid * 16 + lm;   // this thread's pixel (dup x4 across quads)

    // ---- offset GN stats ----
    float means[5], rstds[5];
    const float inv_n = 1.f / (2.f * HW);
#pragma unroll
    for (int g = 0; g < 5; g++) {
        float s  = osum[(b * 5 + g) * 2];
        float s2 = osum[(b * 5 + g) * 2 + 1];
        float mean = s * inv_n;
        float var  = s2 * inv_n - mean * mean;
        means[g] = mean;
        rstds[g] = rsqrtf(var + 1e-5f);
    }

    // ---- offsets (pixel-contiguous) -> sampling base offsets ----
    int   baseA[KK], baseB[KK];
    float wya[KK];
    {
        const float* op = offT + ((size_t)((b * H + h) * W + ps)) * 16;
        f4 o0 = *(const f4*)op;
        f4 o1 = *(const f4*)(op + 4);
        float o8 = op[8];
        float raw[KK] = {o0[0], o0[1], o0[2], o0[3], o1[0], o1[1], o1[2], o1[3], o8};
        float v[KK];
#pragma unroll
        for (int j = 0; j < KK; j++) {
            int g = j >> 1;
            v[j] = fast_tanh((raw[j] - means[g]) * rstds[g] * g_gn_off[j] + b_gn_off[j]);
        }
        float yoff[KK];
        yoff[CENTER] = 0.f;
        float run = 0.f;
#pragma unroll
        for (int k = CENTER - 1; k >= 0; k--) { run += v[k]; yoff[k] = run; }
        run = 0.f;
#pragma unroll
        for (int k = CENTER + 1; k < KK; k++) { run += v[k]; yoff[k] = run; }
#pragma unroll
        for (int k = 0; k < KK; k++) {
            float yc = fminf(fmaxf((float)h + yoff[k], 0.f), (float)(H - 1));
            float fy = floorf(yc);
            int y0 = (int)fy;
            int y1 = min(y0 + 1, H - 1);
            wya[k] = yc - fy;
            int xi = min(max(ps + k - CENTER, 0), W - 1);
            baseA[k] = ((b * HP + y0 + 1) * WP + xi + 1) * 64 + qd * 8;
            baseB[k] = ((b * HP + y1 + 1) * WP + xi + 1) * 64 + qd * 8;
        }
    }

    f4 acc[4];
#pragma unroll
    for (int ct = 0; ct < 4; ct++) acc[ct] = 0;

    // 4 phases: s(2) x tap-half(2); each phase batches all its gathers.
#pragma unroll
    for (int s = 0; s < 2; s++) {
#pragma unroll
        for (int kh = 0; kh < 2; kh++) {
            const int k0 = kh ? 5 : 0;
            const int kn = kh ? 4 : 5;
            uint4 ga[5], gb[5];
#pragma unroll
            for (int k = 0; k < kn; k++) {
                ga[k] = *(const uint4*)(xb + baseA[k0 + k] + s * 32);
                gb[k] = *(const uint4*)(xb + baseB[k0 + k] + s * 32);
            }
#pragma unroll
            for (int k = 0; k < kn; k++) {
                const unsigned short* wk = wb + (k0 + k) * (C * C);
                float fw = wya[k0 + k];
                uint4 r;
                r.x = lerp_pack(ga[k].x, gb[k].x, fw);
                r.y = lerp_pack(ga[k].y, gb[k].y, fw);
                r.z = lerp_pack(ga[k].z, gb[k].z, fw);
                r.w = lerp_pack(ga[k].w, gb[k].w, fw);
                short8 afr = __builtin_bit_cast(short8, r);
#pragma unroll
                for (int ct = 0; ct < 4; ct++) {
                    short8 bfr = *(const short8*)(wk + (ct * 16 + lm) * 64 +
                                                  s * 32 + qd * 8);
                    acc[ct] = __builtin_amdgcn_mfma_f32_16x16x32_bf16(afr, bfr,
                                                                      acc[ct], 0, 0, 0);
                }
            }
        }
    }

    // ---- epilogue: +bias, direct f4 stores, GN partials ----
#pragma unroll
    for (int ct = 0; ct < 4; ct++) {
        int co = ct * 16 + lm;
        float bias = b_dsc[co];
        f4 v;
        float sv = 0.f, sq = 0.f;
#pragma unroll
        for (int r = 0; r < 4; r++) {
            v[r] = acc[ct][r] + bias;
            sv += v[r]; sq += v[r] * v[r];
        }
        *(f4*)(outp + ((size_t)(b * C + co)) * HW + h * W + p0 + wid * 16 + qd * 4) = v;
        sv += __shfl_xor(sv, 16); sv += __shfl_xor(sv, 32);
        sq += __shfl_xor(sq, 16); sq += __shfl_xor(sq, 32);
        if (lane < 16) {
            red[((wid * 4 + ct) * 16 + lm) * 2]     = sv;
            red[((wid * 4 + ct) * 16 + lm) * 2 + 1] = sq;
        }
    }
    __syncthreads();
    if (tid < 128) {
        int co = tid >> 1, comp = tid & 1;
        int ct = co >> 4, lmr = co & 15;
        float s = 0.f;
#pragma unroll
        for (int w2 = 0; w2 < 4; w2++)
            s += red[((w2 * 4 + ct) * 16 + lmr) * 2 + comp];
        atomicAdd(&csum[(b * C + co) * 2 + comp], s);
    }
}

// ---- K3: GN finalize (per block) + apply + ReLU ----
__global__ __launch_bounds__(256) void k_norm(float* __restrict__ outp,
                                              const float* __restrict__ csum,
                                              const float* __restrict__ g_gn,
                                              const float* __restrict__ b_gn) {
    int bid = blockIdx.x;           // 4096: bc(256) x 16
    int bc = bid >> 4;
    int b = bc >> 6, co = bc & 63;
    int grp = co >> 2;
    float S = 0.f, S2 = 0.f;
#pragma unroll
    for (int c2 = 0; c2 < 4; c2++) {
        S  += csum[(b * C + grp * 4 + c2) * 2];
        S2 += csum[(b * C + grp * 4 + c2) * 2 + 1];
    }
    float n = 4.f * HW;
    float mean = S / n;
    float var  = S2 / n - mean * mean;
    float rstd = rsqrtf(var + 1e-5f);
    float sc = rstd * g_gn[co];
    float sh = b_gn[co] - mean * sc;

    int idx = bid * 256 + threadIdx.x;
    float4* ptr = (float4*)outp;
    float4 vv = ptr[idx];
    vv.x = fmaxf(vv.x * sc + sh, 0.f);
    vv.y = fmaxf(vv.y * sc + sh, 0.f);
    vv.z = fmaxf(vv.z * sc + sh, 0.f);
    vv.w = fmaxf(vv.w * sc + sh, 0.f);
    ptr[idx] = vv;
}

extern "C" void kernel_launch(void* const* d_in, const int* in_sizes, int n_in,
                              void* d_out, int out_size, void* d_ws, size_t ws_size,
                              hipStream_t stream) {
    const float* x        = (const float*)d_in[0];
    const float* w_off    = (const float*)d_in[1];
    const float* b_off    = (const float*)d_in[2];
    const float* g_gn_off = (const float*)d_in[3];
    const float* b_gn_off = (const float*)d_in[4];
    const float* w_dsc    = (const float*)d_in[5];
    const float* b_dsc    = (const float*)d_in[6];
    const float* g_gn     = (const float*)d_in[7];
    const float* b_gn     = (const float*)d_in[8];
    float* out = (float*)d_out;
    float* ws  = (float*)d_ws;

    float*          offT = ws + OFF_OFFT;
    unsigned short* xbp  = (unsigned short*)(ws + OFF_XB);
    unsigned short* wbp  = (unsigned short*)(ws + OFF_WB);
    unsigned short* wobp = (unsigned short*)(ws + OFF_WOB);
    float*          csum = ws + OFF_CSUM;
    float*          osum = ws + OFF_OSUM;

    k_prep<<<4 * B * H + 8 + 180 + 1, 256, 0, stream>>>(x, w_dsc, w_off, xbp, wbp,
                                                        wobp, csum);
    k_offconv<<<2 * B * H, 256, 0, stream>>>(xbp, wobp, b_off, offT, osum);
    k_main<<<2 * B * H, 256, 0, stream>>>(xbp, offT, osum, g_gn_off, b_gn_off,
                                          wbp, b_dsc, out, csum);
    k_norm<<<B * C * HW / 4 / 256, 256, 0, stream>>>(out, csum, g_gn, b_gn);
}

// Round 8
// 174.137 us; speedup vs baseline: 1.3511x; 1.2880x over previous
//
#include <hip/hip_runtime.h>
#include <hip/hip_bf16.h>
#include <math.h>

#define B 4
#define C 64
#define H 128
#define W 128
#define KK 9
#define CENTER 4
#define HW (H*W)         // 16384
#define HP 130           // padded height
#define WP 130           // padded width

typedef __attribute__((ext_vector_type(8))) short short8;   // 8 x bf16 (4 VGPRs)
typedef __attribute__((ext_vector_type(4))) float f4;       // MFMA C/D frag

// ---------------- workspace layout (in floats) ----------------
#define OFF_OFFT   0                       // offT: B*H*W*12 = 786432
#define OFF_XB     786432                  // xb: B*130*130*64 bf16 = 2163200 floats
#define OFF_WB     2949632                 // wb: KK*C*C bf16 = 18432 floats
#define OFF_WOB    2968064                 // wob: 9*16*64 bf16 = 4608 floats
#define OFF_CSUM   2972672                 // csum16[16][256][2] = 8192 (zeroed)
#define OFF_OSUM   2980864                 // osum16[16][4][5][2] = 640 (zeroed)
// zero region CSUM..: 9216 floats; total 2981888 floats = 11.93 MB

__device__ __forceinline__ unsigned bf16pack(float a, float b) {
    // round-half-up to bf16; a->low16, b->high16
    unsigned ua = __builtin_bit_cast(unsigned, a) + 0x8000u;
    unsigned ub = __builtin_bit_cast(unsigned, b) + 0x8000u;
    return __builtin_amdgcn_perm(ub, ua, 0x07060302);
}

__device__ __forceinline__ unsigned lerp_pack(unsigned a, unsigned b, float fw) {
    float alo = __builtin_bit_cast(float, a << 16);
    float ahi = __builtin_bit_cast(float, a & 0xffff0000u);
    float blo = __builtin_bit_cast(float, b << 16);
    float bhi = __builtin_bit_cast(float, b & 0xffff0000u);
    float slo = alo + fw * (blo - alo);
    float shi = ahi + fw * (bhi - ahi);
    return bf16pack(slo, shi);
}

__device__ __forceinline__ float fast_tanh(float x) {
    float e = __expf(2.f * x);
    return 1.f - 2.f * __builtin_amdgcn_rcpf(e + 1.f);
}

// ---- K0 (k_prep): transpose (XCD-aligned) + weight converts + zeroing ----
// blocks 0..2047     : x[b][ci][h][w0..+31] -> xb[b][hp][wp][ci] bf16, h=(xcd<<4)|hc
// blocks 2048..2055  : zero border rows hp=0,129
// blocks 2056..2235  : w_dsc -> wb [k][co][ci] ; w_off -> wob [tap][j16][ci]
// blocks 2236..2244  : zero csum16+osum16 (9216 floats)
__global__ __launch_bounds__(256) void k_prep(const float* __restrict__ x,
                                              const float* __restrict__ w_dsc,
                                              const float* __restrict__ w_off,
                                              unsigned short* __restrict__ xb,
                                              unsigned short* __restrict__ wb,
                                              unsigned short* __restrict__ wob,
                                              float* __restrict__ csum) {
    int bid = blockIdx.x;
    int tid = threadIdx.x;
    if (bid < 2048) {
        __shared__ float lt[64 * 33];
        int xcd = bid & 7, i = bid >> 3;
        int c = i & 3, hc = (i >> 2) & 15, b = i >> 6;
        int h = (xcd << 4) | hc;               // same-XCD as consumers of row h
        int w0 = c * 32;
        int ciA = tid >> 2, gA = tid & 3;
        int wlB = tid >> 3, cgB = tid & 7;

        if (c == 0 && tid < 8)
            *(uint4*)(xb + ((size_t)(b * HP + h + 1) * WP) * 64 + tid * 8)
                = make_uint4(0, 0, 0, 0);
        if (c == 3 && tid < 8)
            *(uint4*)(xb + (((size_t)(b * HP + h + 1) * WP) + WP - 1) * 64 + tid * 8)
                = make_uint4(0, 0, 0, 0);
        {
            const float* src = x + ((size_t)(b * C + ciA) * HW) + h * W + w0 + gA * 8;
            float4 v0 = *(const float4*)src;
            float4 v1 = *(const float4*)(src + 4);
            float* d = lt + ciA * 33 + gA * 8;
            d[0] = v0.x; d[1] = v0.y; d[2] = v0.z; d[3] = v0.w;
            d[4] = v1.x; d[5] = v1.y; d[6] = v1.z; d[7] = v1.w;
        }
        __syncthreads();
        {
            unsigned u[4];
#pragma unroll
            for (int i2 = 0; i2 < 4; i2++) {
                float lo = lt[(cgB * 8 + 2 * i2)     * 33 + wlB];
                float hi = lt[(cgB * 8 + 2 * i2 + 1) * 33 + wlB];
                u[i2] = bf16pack(lo, hi);
            }
            *(uint4*)(xb + ((size_t)((b * HP + h + 1) * WP + w0 + wlB + 1)) * 64 + cgB * 8) =
                make_uint4(u[0], u[1], u[2], u[3]);
        }
    } else if (bid < 2048 + 8) {
        int r = bid - 2048;
        int b = r >> 1, which = r & 1;
        unsigned short* dst = xb + ((size_t)(b * HP + which * (HP - 1)) * WP) * 64;
        for (int t = tid; t < WP * 64 / 8; t += 256)
            *(uint4*)(dst + t * 8) = make_uint4(0, 0, 0, 0);
    } else if (bid < 2048 + 8 + 180) {
        int idx = (bid - (2048 + 8)) * 256 + tid;
        if (idx < KK * C * C) {
            int k  = idx >> 12;
            int r  = idx & 4095;
            int co = r >> 6;
            int ci = r & 63;
            unsigned u = __builtin_bit_cast(unsigned, w_dsc[(co * C + ci) * KK + k]);
            u = (u + 0x7fffu + ((u >> 16) & 1u)) >> 16;
            wb[idx] = (unsigned short)u;
        } else if (idx < KK * C * C + 9 * 16 * 64) {
            int r   = idx - KK * C * C;
            int tap = r >> 10;
            int j   = (r >> 6) & 15;
            int ci  = r & 63;
            float v = (j < 10) ? w_off[(j * C + ci) * 9 + tap] : 0.f;
            unsigned u = __builtin_bit_cast(unsigned, v);
            u = (u + 0x7fffu + ((u >> 16) & 1u)) >> 16;
            wob[r] = (unsigned short)u;
        }
    } else {
        int z = bid - (2048 + 8 + 180);
        int base = z * 1024 + tid * 4;       // 9 blocks x 1024 = 9216 floats
        *(f4*)(csum + base) = 0;
    }
}

// ---- K1: offset conv via MFMA, fully batched loads, spread atomics ----
__global__ __launch_bounds__(256, 4) void k_offconv(const unsigned short* __restrict__ xb,
                                                    const unsigned short* __restrict__ wob,
                                                    const float* __restrict__ b_off,
                                                    float* __restrict__ offT,
                                                    float* __restrict__ osum16) {
    __shared__ float red[80];
    int bid = blockIdx.x;          // 1024: xcd(8) x [b(4) x hc(16) x half(2)]
    int xcd  = bid & 7;
    int i    = bid >> 3;
    int b    = i >> 5;
    int rest = i & 31;
    int h    = (xcd << 4) | (rest >> 1);
    int half = rest & 1;
    int tid  = threadIdx.x;
    int wid  = tid >> 6;
    int lane = tid & 63;
    int lm = lane & 15, qd = lane >> 4;
    int pw = half * 64 + wid * 16;           // tile base pixel

    f4 acc = 0;
    const unsigned short* xrow = xb + ((size_t)(b * HP + h) * WP) * 64;  // hp = h+ky
#pragma unroll
    for (int s = 0; s < 2; s++) {
        int co_ofs = s * 32 + qd * 8;
        short8 a_[9], w_[9];
#pragma unroll
        for (int t = 0; t < 9; t++) {
            int ky = t / 3, kx = t - 3 * (t / 3);
            a_[t] = *(const short8*)(xrow +
                ((size_t)(ky * WP + pw + lm + kx)) * 64 + co_ofs);
            w_[t] = *(const short8*)(wob + (t * 16 + lm) * 64 + co_ofs);
        }
#pragma unroll
        for (int t = 0; t < 9; t++)
            acc = __builtin_amdgcn_mfma_f32_16x16x32_bf16(a_[t], w_[t], acc, 0, 0, 0);
    }

    // epilogue: +bias, store offT[p][j] (12-stride), spread-atomic GN sums
    float bo = b_off[lm];
    float sv = 0.f, sq = 0.f;
    int pixbase = (b * H + h) * W;
#pragma unroll
    for (int r = 0; r < 4; r++) {
        float val = acc[r] + bo;
        int p = pw + qd * 4 + r;
        if (lm < 10) {
            offT[(size_t)(pixbase + p) * 12 + lm] = val;
            sv += val; sq += val * val;
        }
    }
    sv += __shfl_xor(sv, 16); sv += __shfl_xor(sv, 32);
    sq += __shfl_xor(sq, 16); sq += __shfl_xor(sq, 32);
    if (lane < 16 && lm < 10) {
        red[(wid * 10 + lm) * 2]     = sv;
        red[(wid * 10 + lm) * 2 + 1] = sq;
    }
    __syncthreads();
    if (tid < 20) {
        int j = tid >> 1, comp = tid & 1;
        float s = red[j * 2 + comp] + red[(10 + j) * 2 + comp] +
                  red[(20 + j) * 2 + comp] + red[(30 + j) * 2 + comp];
        int sidx = (h >> 3) & 15;
        atomicAdd(&osum16[sidx * 40 + b * 10 + (j >> 1) * 2 + comp], s);
    }
}

// ---- K2: fused tanh+cumsum+resample + MFMA 9x1 conv, literal-bound batches ----
__global__ __launch_bounds__(256, 4) void k_main(const unsigned short* __restrict__ xb,
                                                 const float* __restrict__ offT,
                                                 const float* __restrict__ osum16,
                                                 const float* __restrict__ g_gn_off,
                                                 const float* __restrict__ b_gn_off,
                                                 const unsigned short* __restrict__ wb,
                                                 const float* __restrict__ b_dsc,
                                                 float* __restrict__ outp,
                                                 float* __restrict__ csum16) {
    __shared__ float red[512];
    __shared__ float sred[16];

    int bid = blockIdx.x;          // 1024: xcd(8) x [b(4) x hc(16) x half(2)]
    int xcd  = bid & 7;
    int i    = bid >> 3;
    int b    = i >> 5;
    int rest = i & 31;
    int h    = (xcd << 4) | (rest >> 1);
    int p0   = (rest & 1) << 6;
    int tid  = threadIdx.x;
    int wid  = tid >> 6;
    int lane = tid & 63;
    int lm = lane & 15, qd = lane >> 4;

    int ps = p0 + wid * 16 + lm;   // this thread's pixel (dup x4 across quads)

    // ---- reduce spread osum16 -> 10 values in LDS ----
    if (tid < 160) {
        int gc = tid >> 4, s = tid & 15;            // gc = g*2+comp
        float v = osum16[s * 40 + b * 10 + gc];
        v += __shfl_xor(v, 1); v += __shfl_xor(v, 2);
        v += __shfl_xor(v, 4); v += __shfl_xor(v, 8);
        if (s == 0) sred[gc] = v;
    }
    __syncthreads();

    float means[5], rstds[5];
    const float inv_n = 1.f / (2.f * HW);
#pragma unroll
    for (int g = 0; g < 5; g++) {
        float s  = sred[g * 2];
        float s2 = sred[g * 2 + 1];
        float mean = s * inv_n;
        float var  = s2 * inv_n - mean * mean;
        means[g] = mean;
        rstds[g] = rsqrtf(var + 1e-5f);
    }

    // ---- offsets (pixel-contiguous) -> sampling base offsets ----
    int   baseA[KK], baseB[KK];
    float wya[KK];
    {
        const float* op = offT + (size_t)((b * H + h) * W + ps) * 12;
        f4 o0 = *(const f4*)op;
        f4 o1 = *(const f4*)(op + 4);
        float o8 = op[8];
        float raw[KK] = {o0[0], o0[1], o0[2], o0[3], o1[0], o1[1], o1[2], o1[3], o8};
        float v[KK];
#pragma unroll
        for (int j = 0; j < KK; j++) {
            int g = j >> 1;
            v[j] = fast_tanh((raw[j] - means[g]) * rstds[g] * g_gn_off[j] + b_gn_off[j]);
        }
        float yoff[KK];
        yoff[CENTER] = 0.f;
        float run = 0.f;
#pragma unroll
        for (int k = CENTER - 1; k >= 0; k--) { run += v[k]; yoff[k] = run; }
        run = 0.f;
#pragma unroll
        for (int k = CENTER + 1; k < KK; k++) { run += v[k]; yoff[k] = run; }
#pragma unroll
        for (int k = 0; k < KK; k++) {
            float yc = fminf(fmaxf((float)h + yoff[k], 0.f), (float)(H - 1));
            float fy = floorf(yc);
            int y0 = (int)fy;
            int y1 = min(y0 + 1, H - 1);
            wya[k] = yc - fy;
            int xi = min(max(ps + k - CENTER, 0), W - 1);
            baseA[k] = ((b * HP + y0 + 1) * WP + xi + 1) * 64 + qd * 8;
            baseB[k] = ((b * HP + y1 + 1) * WP + xi + 1) * 64 + qd * 8;
        }
    }

    f4 acc[4];
#pragma unroll
    for (int ct = 0; ct < 4; ct++) acc[ct] = 0;

    // K-loop: 2 s-phases x 3 literal groups of 3 taps (6 loads in flight)
#pragma unroll
    for (int s = 0; s < 2; s++) {
        int so = s * 32;
#pragma unroll
        for (int kg = 0; kg < 3; kg++) {
            uint4 ga[3], gb[3];
#pragma unroll
            for (int j = 0; j < 3; j++) {
                ga[j] = *(const uint4*)(xb + baseA[kg * 3 + j] + so);
                gb[j] = *(const uint4*)(xb + baseB[kg * 3 + j] + so);
            }
#pragma unroll
            for (int j = 0; j < 3; j++) {
                int k = kg * 3 + j;
                const unsigned short* wk = wb + k * (C * C);
                float fw = wya[k];
                uint4 r;
                r.x = lerp_pack(ga[j].x, gb[j].x, fw);
                r.y = lerp_pack(ga[j].y, gb[j].y, fw);
                r.z = lerp_pack(ga[j].z, gb[j].z, fw);
                r.w = lerp_pack(ga[j].w, gb[j].w, fw);
                short8 afr = __builtin_bit_cast(short8, r);
#pragma unroll
                for (int ct = 0; ct < 4; ct++) {
                    short8 bfr = *(const short8*)(wk + (ct * 16 + lm) * 64 +
                                                  so + qd * 8);
                    acc[ct] = __builtin_amdgcn_mfma_f32_16x16x32_bf16(afr, bfr,
                                                                      acc[ct], 0, 0, 0);
                }
            }
        }
    }

    // ---- epilogue: +bias, direct f4 stores, spread-atomic GN partials ----
#pragma unroll
    for (int ct = 0; ct < 4; ct++) {
        int co = ct * 16 + lm;
        float bias = b_dsc[co];
        f4 v;
        float sv = 0.f, sq = 0.f;
#pragma unroll
        for (int r = 0; r < 4; r++) {
            v[r] = acc[ct][r] + bias;
            sv += v[r]; sq += v[r] * v[r];
        }
        *(f4*)(outp + ((size_t)(b * C + co)) * HW + h * W + p0 + wid * 16 + qd * 4) = v;
        sv += __shfl_xor(sv, 16); sv += __shfl_xor(sv, 32);
        sq += __shfl_xor(sq, 16); sq += __shfl_xor(sq, 32);
        if (lane < 16) {
            red[((wid * 4 + ct) * 16 + lm) * 2]     = sv;
            red[((wid * 4 + ct) * 16 + lm) * 2 + 1] = sq;
        }
    }
    __syncthreads();
    if (tid < 128) {
        int co = tid >> 1, comp = tid & 1;
        int ct = co >> 4, lmr = co & 15;
        float s = 0.f;
#pragma unroll
        for (int w2 = 0; w2 < 4; w2++)
            s += red[((w2 * 4 + ct) * 16 + lmr) * 2 + comp];
        int sidx = (h >> 3) & 15;
        atomicAdd(&csum16[(sidx * 256 + b * 64 + co) * 2 + comp], s);
    }
}

// ---- K3: GN finalize (reduce csum16 in LDS) + apply + ReLU, XCD-aligned ----
__global__ __launch_bounds__(256) void k_norm(float* __restrict__ outp,
                                              const float* __restrict__ csum16,
                                              const float* __restrict__ g_gn,
                                              const float* __restrict__ b_gn) {
    __shared__ float lds[128];
    int bid = blockIdx.x;           // 4096 = xcd(8) x i(512)
    int xcd = bid & 7;
    int i   = bid >> 3;
    int bc  = i >> 1;
    int c2  = (xcd << 1) | (i & 1); // 8-row chunk index: h = c2*8.. -> same XCD
    int b = bc >> 6, co = bc & 63;
    int grp = co >> 2;
    int tid = threadIdx.x;

    if (tid < 128) {
        int s = tid >> 3, c = (tid >> 1) & 3, comp = tid & 1;
        lds[tid] = csum16[(s * 256 + b * 64 + grp * 4 + c) * 2 + comp];
    }
    __syncthreads();
#pragma unroll
    for (int st = 64; st >= 2; st >>= 1) {
        if (tid < st) lds[tid] += lds[tid + st];
        __syncthreads();
    }
    float S = lds[0], S2 = lds[1];
    float n = 4.f * HW;
    float mean = S / n;
    float var  = S2 / n - mean * mean;
    float rstd = rsqrtf(var + 1e-5f);
    float sc = rstd * g_gn[co];
    float sh = b_gn[co] - mean * sc;

    int idx = (bc * 16 + c2) * 256 + tid;
    float4* ptr = (float4*)outp;
    float4 vv = ptr[idx];
    vv.x = fmaxf(vv.x * sc + sh, 0.f);
    vv.y = fmaxf(vv.y * sc + sh, 0.f);
    vv.z = fmaxf(vv.z * sc + sh, 0.f);
    vv.w = fmaxf(vv.w * sc + sh, 0.f);
    ptr[idx] = vv;
}

extern "C" void kernel_launch(void* const* d_in, const int* in_sizes, int n_in,
                              void* d_out, int out_size, void* d_ws, size_t ws_size,
                              hipStream_t stream) {
    const float* x        = (const float*)d_in[0];
    const float* w_off    = (const float*)d_in[1];
    const float* b_off    = (const float*)d_in[2];
    const float* g_gn_off = (const float*)d_in[3];
    const float* b_gn_off = (const float*)d_in[4];
    const float* w_dsc    = (const float*)d_in[5];
    const float* b_dsc    = (const float*)d_in[6];
    const float* g_gn     = (const float*)d_in[7];
    const float* b_gn     = (const float*)d_in[8];
    float* out = (float*)d_out;
    float* ws  = (float*)d_ws;

    float*          offT   = ws + OFF_OFFT;
    unsigned short* xbp    = (unsigned short*)(ws + OFF_XB);
    unsigned short* wbp    = (unsigned short*)(ws + OFF_WB);
    unsigned short* wobp   = (unsigned short*)(ws + OFF_WOB);
    float*          csum16 = ws + OFF_CSUM;
    float*          osum16 = ws + OFF_OSUM;

    k_prep<<<2048 + 8 + 180 + 9, 256, 0, stream>>>(x, w_dsc, w_off, xbp, wbp,
                                                   wobp, csum16);
    k_offconv<<<2 * B * H, 256, 0, stream>>>(xbp, wobp, b_off, offT, osum16);
    k_main<<<2 * B * H, 256, 0, stream>>>(xbp, offT, osum16, g_gn_off, b_gn_off,
                                          wbp, b_dsc, out, csum16);
    k_norm<<<B * C * HW / 4 / 256, 256, 0, stream>>>(out, csum16, g_gn, b_gn);
}

// Round 9
// 166.871 us; speedup vs baseline: 1.4100x; 1.0435x over previous
//
#include <hip/hip_runtime.h>
#include <hip/hip_bf16.h>
#include <math.h>

#define B 4
#define C 64
#define H 128
#define W 128
#define KK 9
#define CENTER 4
#define HW (H*W)         // 16384
#define HP 130           // padded height
#define WP 130           // padded width

typedef __attribute__((ext_vector_type(8))) short short8;   // 8 x bf16 (4 VGPRs)
typedef __attribute__((ext_vector_type(4))) float f4;       // MFMA C/D frag

// ---------------- workspace layout (in floats) ----------------
#define OFF_OFFT   0                       // offT: B*H*W*12 = 786432
#define OFF_XB     786432                  // xb: B*130*130*64 bf16 = 2163200 floats
#define OFF_WB     2949632                 // wb: KK*C*C bf16 = 18432 floats
#define OFF_WOB    2968064                 // wob: 9*16*64 bf16 = 4608 floats
#define OFF_CSUM   2972672                 // csum16[16][256][2] = 8192 (zeroed)
#define OFF_OSUM   2980864                 // osum16[16][4][5][2] = 640 (zeroed)
// zero region CSUM..: 9216 floats; total 2981888 floats = 11.93 MB

__device__ __forceinline__ unsigned bf16pack(float a, float b) {
    // round-half-up to bf16; a->low16, b->high16
    unsigned ua = __builtin_bit_cast(unsigned, a) + 0x8000u;
    unsigned ub = __builtin_bit_cast(unsigned, b) + 0x8000u;
    return __builtin_amdgcn_perm(ub, ua, 0x07060302);
}

__device__ __forceinline__ unsigned lerp_pack(unsigned a, unsigned b, float fw) {
    float alo = __builtin_bit_cast(float, a << 16);
    float ahi = __builtin_bit_cast(float, a & 0xffff0000u);
    float blo = __builtin_bit_cast(float, b << 16);
    float bhi = __builtin_bit_cast(float, b & 0xffff0000u);
    float slo = alo + fw * (blo - alo);
    float shi = ahi + fw * (bhi - ahi);
    return bf16pack(slo, shi);
}

__device__ __forceinline__ float fast_tanh(float x) {
    float e = __expf(2.f * x);
    return 1.f - 2.f * __builtin_amdgcn_rcpf(e + 1.f);
}

// ---- K0 (k_prep): transpose (XCD-aligned) + weight converts + zeroing ----
__global__ __launch_bounds__(256) void k_prep(const float* __restrict__ x,
                                              const float* __restrict__ w_dsc,
                                              const float* __restrict__ w_off,
                                              unsigned short* __restrict__ xb,
                                              unsigned short* __restrict__ wb,
                                              unsigned short* __restrict__ wob,
                                              float* __restrict__ csum) {
    int bid = blockIdx.x;
    int tid = threadIdx.x;
    if (bid < 2048) {
        __shared__ float lt[64 * 33];
        int xcd = bid & 7, i = bid >> 3;
        int c = i & 3, hc = (i >> 2) & 15, b = i >> 6;
        int h = (xcd << 4) | hc;               // same-XCD as consumers of row h
        int w0 = c * 32;
        int ciA = tid >> 2, gA = tid & 3;
        int wlB = tid >> 3, cgB = tid & 7;

        if (c == 0 && tid < 8)
            *(uint4*)(xb + ((size_t)(b * HP + h + 1) * WP) * 64 + tid * 8)
                = make_uint4(0, 0, 0, 0);
        if (c == 3 && tid < 8)
            *(uint4*)(xb + (((size_t)(b * HP + h + 1) * WP) + WP - 1) * 64 + tid * 8)
                = make_uint4(0, 0, 0, 0);
        {
            const float* src = x + ((size_t)(b * C + ciA) * HW) + h * W + w0 + gA * 8;
            float4 v0 = *(const float4*)src;
            float4 v1 = *(const float4*)(src + 4);
            float* d = lt + ciA * 33 + gA * 8;
            d[0] = v0.x; d[1] = v0.y; d[2] = v0.z; d[3] = v0.w;
            d[4] = v1.x; d[5] = v1.y; d[6] = v1.z; d[7] = v1.w;
        }
        __syncthreads();
        {
            unsigned u[4];
#pragma unroll
            for (int i2 = 0; i2 < 4; i2++) {
                float lo = lt[(cgB * 8 + 2 * i2)     * 33 + wlB];
                float hi = lt[(cgB * 8 + 2 * i2 + 1) * 33 + wlB];
                u[i2] = bf16pack(lo, hi);
            }
            *(uint4*)(xb + ((size_t)((b * HP + h + 1) * WP + w0 + wlB + 1)) * 64 + cgB * 8) =
                make_uint4(u[0], u[1], u[2], u[3]);
        }
    } else if (bid < 2048 + 8) {
        int r = bid - 2048;
        int b = r >> 1, which = r & 1;
        unsigned short* dst = xb + ((size_t)(b * HP + which * (HP - 1)) * WP) * 64;
        for (int t = tid; t < WP * 64 / 8; t += 256)
            *(uint4*)(dst + t * 8) = make_uint4(0, 0, 0, 0);
    } else if (bid < 2048 + 8 + 180) {
        int idx = (bid - (2048 + 8)) * 256 + tid;
        if (idx < KK * C * C) {
            int k  = idx >> 12;
            int r  = idx & 4095;
            int co = r >> 6;
            int ci = r & 63;
            unsigned u = __builtin_bit_cast(unsigned, w_dsc[(co * C + ci) * KK + k]);
            u = (u + 0x7fffu + ((u >> 16) & 1u)) >> 16;
            wb[idx] = (unsigned short)u;
        } else if (idx < KK * C * C + 9 * 16 * 64) {
            int r   = idx - KK * C * C;
            int tap = r >> 10;
            int j   = (r >> 6) & 15;
            int ci  = r & 63;
            float v = (j < 10) ? w_off[(j * C + ci) * 9 + tap] : 0.f;
            unsigned u = __builtin_bit_cast(unsigned, v);
            u = (u + 0x7fffu + ((u >> 16) & 1u)) >> 16;
            wob[r] = (unsigned short)u;
        }
    } else {
        int z = bid - (2048 + 8 + 180);
        int base = z * 1024 + tid * 4;       // 9 blocks x 1024 = 9216 floats
        *(f4*)(csum + base) = 0;
    }
}

// ---- K1: offset conv via MFMA, fully batched loads, spread atomics ----
__global__ __launch_bounds__(256, 4) void k_offconv(const unsigned short* __restrict__ xb,
                                                    const unsigned short* __restrict__ wob,
                                                    const float* __restrict__ b_off,
                                                    float* __restrict__ offT,
                                                    float* __restrict__ osum16) {
    __shared__ float red[80];
    int bid = blockIdx.x;          // 1024: xcd(8) x [b(4) x hc(16) x half(2)]
    int xcd  = bid & 7;
    int i    = bid >> 3;
    int b    = i >> 5;
    int rest = i & 31;
    int h    = (xcd << 4) | (rest >> 1);
    int half = rest & 1;
    int tid  = threadIdx.x;
    int wid  = tid >> 6;
    int lane = tid & 63;
    int lm = lane & 15, qd = lane >> 4;
    int pw = half * 64 + wid * 16;           // tile base pixel

    f4 acc = 0;
    const unsigned short* xrow = xb + ((size_t)(b * HP + h) * WP) * 64;  // hp = h+ky
#pragma unroll
    for (int s = 0; s < 2; s++) {
        int co_ofs = s * 32 + qd * 8;
        short8 a_[9], w_[9];
#pragma unroll
        for (int t = 0; t < 9; t++) {
            int ky = t / 3, kx = t - 3 * (t / 3);
            a_[t] = *(const short8*)(xrow +
                ((size_t)(ky * WP + pw + lm + kx)) * 64 + co_ofs);
            w_[t] = *(const short8*)(wob + (t * 16 + lm) * 64 + co_ofs);
        }
#pragma unroll
        for (int t = 0; t < 9; t++)
            acc = __builtin_amdgcn_mfma_f32_16x16x32_bf16(a_[t], w_[t], acc, 0, 0, 0);
    }

    // epilogue: +bias, store offT[p][j] (12-stride), spread-atomic GN sums
    float bo = b_off[lm];
    float sv = 0.f, sq = 0.f;
    int pixbase = (b * H + h) * W;
#pragma unroll
    for (int r = 0; r < 4; r++) {
        float val = acc[r] + bo;
        int p = pw + qd * 4 + r;
        if (lm < 10) {
            offT[(size_t)(pixbase + p) * 12 + lm] = val;
            sv += val; sq += val * val;
        }
    }
    sv += __shfl_xor(sv, 16); sv += __shfl_xor(sv, 32);
    sq += __shfl_xor(sq, 16); sq += __shfl_xor(sq, 32);
    if (lane < 16 && lm < 10) {
        red[(wid * 10 + lm) * 2]     = sv;
        red[(wid * 10 + lm) * 2 + 1] = sq;
    }
    __syncthreads();
    if (tid < 20) {
        int j = tid >> 1, comp = tid & 1;
        float s = red[j * 2 + comp] + red[(10 + j) * 2 + comp] +
                  red[(20 + j) * 2 + comp] + red[(30 + j) * 2 + comp];
        int sidx = (h >> 3) & 15;
        atomicAdd(&osum16[sidx * 40 + b * 10 + (j >> 1) * 2 + comp], s);
    }
}

// ---- K2: fused tanh+cumsum+resample + MFMA 9x1 conv ----
// In-loop coordinate computation: only yoff[9]+acc live across K-loop (no spill).
__global__ __launch_bounds__(256, 4) void k_main(const unsigned short* __restrict__ xb,
                                                 const float* __restrict__ offT,
                                                 const float* __restrict__ osum16,
                                                 const float* __restrict__ g_gn_off,
                                                 const float* __restrict__ b_gn_off,
                                                 const unsigned short* __restrict__ wb,
                                                 const float* __restrict__ b_dsc,
                                                 float* __restrict__ outp,
                                                 float* __restrict__ csum16) {
    __shared__ float red[512];
    __shared__ float sred[16];

    int bid = blockIdx.x;          // 1024: xcd(8) x [b(4) x hc(16) x half(2)]
    int xcd  = bid & 7;
    int i    = bid >> 3;
    int b    = i >> 5;
    int rest = i & 31;
    int h    = (xcd << 4) | (rest >> 1);
    int p0   = (rest & 1) << 6;
    int tid  = threadIdx.x;
    int wid  = tid >> 6;
    int lane = tid & 63;
    int lm = lane & 15, qd = lane >> 4;

    int ps = p0 + wid * 16 + lm;   // this thread's pixel (dup x4 across quads)

    // ---- reduce spread osum16 -> 10 values in LDS ----
    if (tid < 160) {
        int gc = tid >> 4, s = tid & 15;            // gc = g*2+comp
        float v = osum16[s * 40 + b * 10 + gc];
        v += __shfl_xor(v, 1); v += __shfl_xor(v, 2);
        v += __shfl_xor(v, 4); v += __shfl_xor(v, 8);
        if (s == 0) sred[gc] = v;
    }
    __syncthreads();

    // ---- prologue: offsets -> yoff[9] (means/rstds die here) ----
    float yoff[KK];
    {
        const float inv_n = 1.f / (2.f * HW);
        const float* op = offT + (size_t)((b * H + h) * W + ps) * 12;
        f4 o0 = *(const f4*)op;
        f4 o1 = *(const f4*)(op + 4);
        float o8 = op[8];
        float raw[KK] = {o0[0], o0[1], o0[2], o0[3], o1[0], o1[1], o1[2], o1[3], o8};
        float v[KK];
#pragma unroll
        for (int j = 0; j < KK; j++) {
            int g = j >> 1;
            float s  = sred[g * 2];
            float s2 = sred[g * 2 + 1];
            float mean = s * inv_n;
            float var  = s2 * inv_n - mean * mean;
            float rstd = rsqrtf(var + 1e-5f);
            v[j] = fast_tanh((raw[j] - mean) * rstd * g_gn_off[j] + b_gn_off[j]);
        }
        yoff[CENTER] = 0.f;
        float run = 0.f;
#pragma unroll
        for (int k = CENTER - 1; k >= 0; k--) { run += v[k]; yoff[k] = run; }
        run = 0.f;
#pragma unroll
        for (int k = CENTER + 1; k < KK; k++) { run += v[k]; yoff[k] = run; }
    }

    f4 acc[4];
#pragma unroll
    for (int ct = 0; ct < 4; ct++) acc[ct] = 0;

    // K-loop: 3 groups of 3 taps; coords computed in-group, 6 loads in flight.
#pragma unroll
    for (int kg = 0; kg < 3; kg++) {
        int   ofsA[3], ofsB[3];
        float fw[3];
#pragma unroll
        for (int j = 0; j < 3; j++) {
            int k = kg * 3 + j;
            float yc = fminf(fmaxf((float)h + yoff[k], 0.f), (float)(H - 1));
            float fy = floorf(yc);
            int y0 = (int)fy;
            int dy = (y0 < H - 1) ? (WP * 64) : 0;
            fw[j] = yc - fy;
            int xi = min(max(ps + k - CENTER, 0), W - 1);
            ofsA[j] = ((b * HP + y0 + 1) * WP + xi + 1) * 64 + qd * 8;
            ofsB[j] = ofsA[j] + dy;
        }
#pragma unroll
        for (int s = 0; s < 2; s++) {
            int so = s * 32;
            uint4 ga[3], gb[3];
#pragma unroll
            for (int j = 0; j < 3; j++) {
                ga[j] = *(const uint4*)(xb + ofsA[j] + so);
                gb[j] = *(const uint4*)(xb + ofsB[j] + so);
            }
#pragma unroll
            for (int j = 0; j < 3; j++) {
                int k = kg * 3 + j;
                const unsigned short* wk = wb + k * (C * C);
                uint4 r;
                r.x = lerp_pack(ga[j].x, gb[j].x, fw[j]);
                r.y = lerp_pack(ga[j].y, gb[j].y, fw[j]);
                r.z = lerp_pack(ga[j].z, gb[j].z, fw[j]);
                r.w = lerp_pack(ga[j].w, gb[j].w, fw[j]);
                short8 afr = __builtin_bit_cast(short8, r);
#pragma unroll
                for (int ct = 0; ct < 4; ct++) {
                    short8 bfr = *(const short8*)(wk + (ct * 16 + lm) * 64 +
                                                  so + qd * 8);
                    acc[ct] = __builtin_amdgcn_mfma_f32_16x16x32_bf16(afr, bfr,
                                                                      acc[ct], 0, 0, 0);
                }
            }
        }
    }

    // ---- epilogue: +bias, direct f4 stores, spread-atomic GN partials ----
#pragma unroll
    for (int ct = 0; ct < 4; ct++) {
        int co = ct * 16 + lm;
        float bias = b_dsc[co];
        f4 v;
        float sv = 0.f, sq = 0.f;
#pragma unroll
        for (int r = 0; r < 4; r++) {
            v[r] = acc[ct][r] + bias;
            sv += v[r]; sq += v[r] * v[r];
        }
        *(f4*)(outp + ((size_t)(b * C + co)) * HW + h * W + p0 + wid * 16 + qd * 4) = v;
        sv += __shfl_xor(sv, 16); sv += __shfl_xor(sv, 32);
        sq += __shfl_xor(sq, 16); sq += __shfl_xor(sq, 32);
        if (lane < 16) {
            red[((wid * 4 + ct) * 16 + lm) * 2]     = sv;
            red[((wid * 4 + ct) * 16 + lm) * 2 + 1] = sq;
        }
    }
    __syncthreads();
    if (tid < 128) {
        int co = tid >> 1, comp = tid & 1;
        int ct = co >> 4, lmr = co & 15;
        float s = 0.f;
#pragma unroll
        for (int w2 = 0; w2 < 4; w2++)
            s += red[((w2 * 4 + ct) * 16 + lmr) * 2 + comp];
        int sidx = (h >> 3) & 15;
        atomicAdd(&csum16[(sidx * 256 + b * 64 + co) * 2 + comp], s);
    }
}

// ---- K3: GN finalize (reduce csum16 in LDS) + apply + ReLU, XCD-aligned ----
__global__ __launch_bounds__(256) void k_norm(float* __restrict__ outp,
                                              const float* __restrict__ csum16,
                                              const float* __restrict__ g_gn,
                                              const float* __restrict__ b_gn) {
    __shared__ float lds[128];
    int bid = blockIdx.x;           // 4096 = xcd(8) x i(512)
    int xcd = bid & 7;
    int i   = bid >> 3;
    int bc  = i >> 1;
    int c2  = (xcd << 1) | (i & 1); // 8-row chunk index: h = c2*8.. -> same XCD
    int b = bc >> 6, co = bc & 63;
    int grp = co >> 2;
    int tid = threadIdx.x;

    if (tid < 128) {
        int s = tid >> 3, c = (tid >> 1) & 3, comp = tid & 1;
        lds[tid] = csum16[(s * 256 + b * 64 + grp * 4 + c) * 2 + comp];
    }
    __syncthreads();
#pragma unroll
    for (int st = 64; st >= 2; st >>= 1) {
        if (tid < st) lds[tid] += lds[tid + st];
        __syncthreads();
    }
    float S = lds[0], S2 = lds[1];
    float n = 4.f * HW;
    float mean = S / n;
    float var  = S2 / n - mean * mean;
    float rstd = rsqrtf(var + 1e-5f);
    float sc = rstd * g_gn[co];
    float sh = b_gn[co] - mean * sc;

    int idx = (bc * 16 + c2) * 256 + tid;
    float4* ptr = (float4*)outp;
    float4 vv = ptr[idx];
    vv.x = fmaxf(vv.x * sc + sh, 0.f);
    vv.y = fmaxf(vv.y * sc + sh, 0.f);
    vv.z = fmaxf(vv.z * sc + sh, 0.f);
    vv.w = fmaxf(vv.w * sc + sh, 0.f);
    ptr[idx] = vv;
}

extern "C" void kernel_launch(void* const* d_in, const int* in_sizes, int n_in,
                              void* d_out, int out_size, void* d_ws, size_t ws_size,
                              hipStream_t stream) {
    const float* x        = (const float*)d_in[0];
    const float* w_off    = (const float*)d_in[1];
    const float* b_off    = (const float*)d_in[2];
    const float* g_gn_off = (const float*)d_in[3];
    const float* b_gn_off = (const float*)d_in[4];
    const float* w_dsc    = (const float*)d_in[5];
    const float* b_dsc    = (const float*)d_in[6];
    const float* g_gn     = (const float*)d_in[7];
    const float* b_gn     = (const float*)d_in[8];
    float* out = (float*)d_out;
    float* ws  = (float*)d_ws;

    float*          offT   = ws + OFF_OFFT;
    unsigned short* xbp    = (unsigned short*)(ws + OFF_XB);
    unsigned short* wbp    = (unsigned short*)(ws + OFF_WB);
    unsigned short* wobp   = (unsigned short*)(ws + OFF_WOB);
    float*          csum16 = ws + OFF_CSUM;
    float*          osum16 = ws + OFF_OSUM;

    k_prep<<<2048 + 8 + 180 + 9, 256, 0, stream>>>(x, w_dsc, w_off, xbp, wbp,
                                                   wobp, csum16);
    k_offconv<<<2 * B * H, 256, 0, stream>>>(xbp, wobp, b_off, offT, osum16);
    k_main<<<2 * B * H, 256, 0, stream>>>(xbp, offT, osum16, g_gn_off, b_gn_off,
                                          wbp, b_dsc, out, csum16);
    k_norm<<<B * C * HW / 4 / 256, 256, 0, stream>>>(out, csum16, g_gn, b_gn);
}

// Round 10
// 134.911 us; speedup vs baseline: 1.7440x; 1.2369x over previous
//
#include <hip/hip_runtime.h>
#include <hip/hip_bf16.h>
#include <math.h>

#define B 4
#define C 64
#define H 128
#define W 128
#define KK 9
#define CENTER 4
#define HW (H*W)         // 16384
#define HP 130           // padded height
#define WP 130           // padded width

typedef __attribute__((ext_vector_type(8))) short short8;   // 8 x bf16 (4 VGPRs)
typedef __attribute__((ext_vector_type(4))) float f4;       // MFMA C/D frag

// ---------------- workspace layout (in floats) ----------------
#define OFF_OFFT   0                       // offT: B*H*W*12 = 786432
#define OFF_XB     786432                  // xb: B*130*130*64 bf16 = 2163200 floats
#define OFF_WB     2949632                 // wb: KK*C*C bf16 = 18432 floats
#define OFF_WOB    2968064                 // wob: 9*16*64 bf16 = 4608 floats
#define OFF_CSUM   2972672                 // csum16[16][256][2] = 8192 (zeroed)
#define OFF_OSUM   2980864                 // osum16[16][4][5][2] = 640 (zeroed)
// zero region CSUM..: 9216 floats; total 2981888 floats = 11.93 MB

__device__ __forceinline__ unsigned bf16pack(float a, float b) {
    // round-half-up to bf16; a->low16, b->high16
    unsigned ua = __builtin_bit_cast(unsigned, a) + 0x8000u;
    unsigned ub = __builtin_bit_cast(unsigned, b) + 0x8000u;
    return __builtin_amdgcn_perm(ub, ua, 0x07060302);
}

__device__ __forceinline__ unsigned lerp_pack(unsigned a, unsigned b, float fw) {
    float alo = __builtin_bit_cast(float, a << 16);
    float ahi = __builtin_bit_cast(float, a & 0xffff0000u);
    float blo = __builtin_bit_cast(float, b << 16);
    float bhi = __builtin_bit_cast(float, b & 0xffff0000u);
    float slo = alo + fw * (blo - alo);
    float shi = ahi + fw * (bhi - ahi);
    return bf16pack(slo, shi);
}

__device__ __forceinline__ float fast_tanh(float x) {
    float e = __expf(2.f * x);
    return 1.f - 2.f * __builtin_amdgcn_rcpf(e + 1.f);
}

// ---- K0 (k_prep): transpose (XCD-aligned) + weight converts + zeroing ----
__global__ __launch_bounds__(256) void k_prep(const float* __restrict__ x,
                                              const float* __restrict__ w_dsc,
                                              const float* __restrict__ w_off,
                                              unsigned short* __restrict__ xb,
                                              unsigned short* __restrict__ wb,
                                              unsigned short* __restrict__ wob,
                                              float* __restrict__ csum) {
    int bid = blockIdx.x;
    int tid = threadIdx.x;
    if (bid < 2048) {
        __shared__ float lt[64 * 33];
        int xcd = bid & 7, i = bid >> 3;
        int c = i & 3, hc = (i >> 2) & 15, b = i >> 6;
        int h = (xcd << 4) | hc;               // same-XCD as consumers of row h
        int w0 = c * 32;
        int ciA = tid >> 2, gA = tid & 3;
        int wlB = tid >> 3, cgB = tid & 7;

        if (c == 0 && tid < 8)
            *(uint4*)(xb + ((size_t)(b * HP + h + 1) * WP) * 64 + tid * 8)
                = make_uint4(0, 0, 0, 0);
        if (c == 3 && tid < 8)
            *(uint4*)(xb + (((size_t)(b * HP + h + 1) * WP) + WP - 1) * 64 + tid * 8)
                = make_uint4(0, 0, 0, 0);
        {
            const float* src = x + ((size_t)(b * C + ciA) * HW) + h * W + w0 + gA * 8;
            float4 v0 = *(const float4*)src;
            float4 v1 = *(const float4*)(src + 4);
            float* d = lt + ciA * 33 + gA * 8;
            d[0] = v0.x; d[1] = v0.y; d[2] = v0.z; d[3] = v0.w;
            d[4] = v1.x; d[5] = v1.y; d[6] = v1.z; d[7] = v1.w;
        }
        __syncthreads();
        {
            unsigned u[4];
#pragma unroll
            for (int i2 = 0; i2 < 4; i2++) {
                float lo = lt[(cgB * 8 + 2 * i2)     * 33 + wlB];
                float hi = lt[(cgB * 8 + 2 * i2 + 1) * 33 + wlB];
                u[i2] = bf16pack(lo, hi);
            }
            *(uint4*)(xb + ((size_t)((b * HP + h + 1) * WP + w0 + wlB + 1)) * 64 + cgB * 8) =
                make_uint4(u[0], u[1], u[2], u[3]);
        }
    } else if (bid < 2048 + 8) {
        int r = bid - 2048;
        int b = r >> 1, which = r & 1;
        unsigned short* dst = xb + ((size_t)(b * HP + which * (HP - 1)) * WP) * 64;
        for (int t = tid; t < WP * 64 / 8; t += 256)
            *(uint4*)(dst + t * 8) = make_uint4(0, 0, 0, 0);
    } else if (bid < 2048 + 8 + 180) {
        int idx = (bid - (2048 + 8)) * 256 + tid;
        if (idx < KK * C * C) {
            int k  = idx >> 12;
            int r  = idx & 4095;
            int co = r >> 6;
            int ci = r & 63;
            unsigned u = __builtin_bit_cast(unsigned, w_dsc[(co * C + ci) * KK + k]);
            u = (u + 0x7fffu + ((u >> 16) & 1u)) >> 16;
            wb[idx] = (unsigned short)u;
        } else if (idx < KK * C * C + 9 * 16 * 64) {
            int r   = idx - KK * C * C;
            int tap = r >> 10;
            int j   = (r >> 6) & 15;
            int ci  = r & 63;
            float v = (j < 10) ? w_off[(j * C + ci) * 9 + tap] : 0.f;
            unsigned u = __builtin_bit_cast(unsigned, v);
            u = (u + 0x7fffu + ((u >> 16) & 1u)) >> 16;
            wob[r] = (unsigned short)u;
        }
    } else {
        int z = bid - (2048 + 8 + 180);
        int base = z * 1024 + tid * 4;       // 9 blocks x 1024 = 9216 floats
        *(f4*)(csum + base) = 0;
    }
}

// ---- K1: offset conv via MFMA, LDS-staged weights, spread atomics ----
__global__ __launch_bounds__(256, 4) void k_offconv(const unsigned short* __restrict__ xb,
                                                    const unsigned short* __restrict__ wob,
                                                    const float* __restrict__ b_off,
                                                    float* __restrict__ offT,
                                                    float* __restrict__ osum16) {
    // wlds chunk layout: (g ^ (row&7))*144 + row, row = tap*16+j (144), g 0..7
    __shared__ unsigned short wlds[1152 * 8];   // 18432 B
    __shared__ float red[80];
    int bid = blockIdx.x;          // 1024: xcd(8) x [b(4) x hc(16) x half(2)]
    int xcd  = bid & 7;
    int i    = bid >> 3;
    int b    = i >> 5;
    int rest = i & 31;
    int h    = (xcd << 4) | (rest >> 1);
    int half = rest & 1;
    int tid  = threadIdx.x;
    int wid  = tid >> 6;
    int lane = tid & 63;
    int lm = lane & 15, qd = lane >> 4;
    int pw = half * 64 + wid * 16;           // tile base pixel

    // stage wob -> LDS (swizzled)
    for (int c = tid; c < 1152; c += 256) {
        int row = c >> 3, g = c & 7;
        uint4 v = *(const uint4*)(wob + c * 8);
        int dst = (g ^ (row & 7)) * 144 + row;
        *(uint4*)(wlds + dst * 8) = v;
    }
    __syncthreads();

    f4 acc = 0;
    const unsigned short* xrow = xb + ((size_t)(b * HP + h) * WP) * 64;  // hp = h+ky
#pragma unroll
    for (int s = 0; s < 2; s++) {
        int co_ofs = s * 32 + qd * 8;
        short8 a_[9];
#pragma unroll
        for (int t = 0; t < 9; t++) {
            int ky = t / 3, kx = t - 3 * (t / 3);
            a_[t] = *(const short8*)(xrow +
                ((size_t)(ky * WP + pw + lm + kx)) * 64 + co_ofs);
        }
#pragma unroll
        for (int t = 0; t < 9; t++) {
            int row = t * 16 + lm;
            int chunk = (((s * 4 + qd) ^ (lm & 7)) * 144) + row;
            short8 w = *(const short8*)(wlds + chunk * 8);
            acc = __builtin_amdgcn_mfma_f32_16x16x32_bf16(a_[t], w, acc, 0, 0, 0);
        }
    }

    // epilogue: +bias, store offT[p][j] (12-stride), spread-atomic GN sums
    float bo = b_off[lm];
    float sv = 0.f, sq = 0.f;
    int pixbase = (b * H + h) * W;
#pragma unroll
    for (int r = 0; r < 4; r++) {
        float val = acc[r] + bo;
        int p = pw + qd * 4 + r;
        if (lm < 10) {
            offT[(size_t)(pixbase + p) * 12 + lm] = val;
            sv += val; sq += val * val;
        }
    }
    sv += __shfl_xor(sv, 16); sv += __shfl_xor(sv, 32);
    sq += __shfl_xor(sq, 16); sq += __shfl_xor(sq, 32);
    if (lane < 16 && lm < 10) {
        red[(wid * 10 + lm) * 2]     = sv;
        red[(wid * 10 + lm) * 2 + 1] = sq;
    }
    __syncthreads();
    if (tid < 20) {
        int j = tid >> 1, comp = tid & 1;
        float s = red[j * 2 + comp] + red[(10 + j) * 2 + comp] +
                  red[(20 + j) * 2 + comp] + red[(30 + j) * 2 + comp];
        int sidx = (h >> 3) & 15;
        atomicAdd(&osum16[sidx * 40 + b * 10 + (j >> 1) * 2 + comp], s);
    }
}

// ---- K2: fused tanh+cumsum+resample + MFMA 9x1 conv, LDS-staged weights ----
// s-outer: stage 36.9 KB s-half of wb, run 3 tap-groups, restage, repeat.
__global__ __launch_bounds__(256, 4) void k_main(const unsigned short* __restrict__ xb,
                                                 const float* __restrict__ offT,
                                                 const float* __restrict__ osum16,
                                                 const float* __restrict__ g_gn_off,
                                                 const float* __restrict__ b_gn_off,
                                                 const unsigned short* __restrict__ wb,
                                                 const float* __restrict__ b_dsc,
                                                 float* __restrict__ outp,
                                                 float* __restrict__ csum16) {
    // wlds chunk layout (per s-half): (g2 ^ (row&3))*576 + k*64 + row
    __shared__ unsigned short wlds[2304 * 8];   // 36864 B
    __shared__ float red[512];
    __shared__ float sred[16];

    int bid = blockIdx.x;          // 1024: xcd(8) x [b(4) x hc(16) x half(2)]
    int xcd  = bid & 7;
    int i    = bid >> 3;
    int b    = i >> 5;
    int rest = i & 31;
    int h    = (xcd << 4) | (rest >> 1);
    int p0   = (rest & 1) << 6;
    int tid  = threadIdx.x;
    int wid  = tid >> 6;
    int lane = tid & 63;
    int lm = lane & 15, qd = lane >> 4;

    int ps = p0 + wid * 16 + lm;   // this thread's pixel (dup x4 across quads)

    // ---- reduce spread osum16 -> 10 values in LDS ----
    if (tid < 160) {
        int gc = tid >> 4, s = tid & 15;            // gc = g*2+comp
        float v = osum16[s * 40 + b * 10 + gc];
        v += __shfl_xor(v, 1); v += __shfl_xor(v, 2);
        v += __shfl_xor(v, 4); v += __shfl_xor(v, 8);
        if (s == 0) sred[gc] = v;
    }
    // ---- stage s=0 weight half (overlaps with sred) ----
    for (int c = tid; c < 2304; c += 256) {
        int k = c >> 8, row = (c >> 2) & 63, g2 = c & 3;
        uint4 v = *(const uint4*)(wb + (size_t)k * 4096 + row * 64 + g2 * 8);
        int dst = ((g2 ^ (row & 3)) * 576) + k * 64 + row;
        *(uint4*)(wlds + dst * 8) = v;
    }
    __syncthreads();

    // ---- prologue: offsets -> yoff[9] ----
    float yoff[KK];
    {
        const float inv_n = 1.f / (2.f * HW);
        const float* op = offT + (size_t)((b * H + h) * W + ps) * 12;
        f4 o0 = *(const f4*)op;
        f4 o1 = *(const f4*)(op + 4);
        float o8 = op[8];
        float raw[KK] = {o0[0], o0[1], o0[2], o0[3], o1[0], o1[1], o1[2], o1[3], o8};
        float v[KK];
#pragma unroll
        for (int j = 0; j < KK; j++) {
            int g = j >> 1;
            float s  = sred[g * 2];
            float s2 = sred[g * 2 + 1];
            float mean = s * inv_n;
            float var  = s2 * inv_n - mean * mean;
            float rstd = rsqrtf(var + 1e-5f);
            v[j] = fast_tanh((raw[j] - mean) * rstd * g_gn_off[j] + b_gn_off[j]);
        }
        yoff[CENTER] = 0.f;
        float run = 0.f;
#pragma unroll
        for (int k = CENTER - 1; k >= 0; k--) { run += v[k]; yoff[k] = run; }
        run = 0.f;
#pragma unroll
        for (int k = CENTER + 1; k < KK; k++) { run += v[k]; yoff[k] = run; }
    }

    f4 acc[4];
#pragma unroll
    for (int ct = 0; ct < 4; ct++) acc[ct] = 0;

    // one s-pass over all 9 taps (weights for this s are in LDS)
    auto kpass = [&](int s) {
        int so = s * 32;
#pragma unroll
        for (int kg = 0; kg < 3; kg++) {
            int   ofsA[3], ofsB[3];
            float fw[3];
#pragma unroll
            for (int j = 0; j < 3; j++) {
                int k = kg * 3 + j;
                float yc = fminf(fmaxf((float)h + yoff[k], 0.f), (float)(H - 1));
                float fy = floorf(yc);
                int y0 = (int)fy;
                int dy = (y0 < H - 1) ? (WP * 64) : 0;
                fw[j] = yc - fy;
                int xi = min(max(ps + k - CENTER, 0), W - 1);
                ofsA[j] = ((b * HP + y0 + 1) * WP + xi + 1) * 64 + qd * 8 + so;
                ofsB[j] = ofsA[j] + dy;
            }
            uint4 ga[3], gb[3];
#pragma unroll
            for (int j = 0; j < 3; j++) {
                ga[j] = *(const uint4*)(xb + ofsA[j]);
                gb[j] = *(const uint4*)(xb + ofsB[j]);
            }
#pragma unroll
            for (int j = 0; j < 3; j++) {
                int k = kg * 3 + j;
                uint4 r;
                r.x = lerp_pack(ga[j].x, gb[j].x, fw[j]);
                r.y = lerp_pack(ga[j].y, gb[j].y, fw[j]);
                r.z = lerp_pack(ga[j].z, gb[j].z, fw[j]);
                r.w = lerp_pack(ga[j].w, gb[j].w, fw[j]);
                short8 afr = __builtin_bit_cast(short8, r);
#pragma unroll
                for (int ct = 0; ct < 4; ct++) {
                    int row = ct * 16 + lm;
                    int chunk = ((qd ^ (lm & 3)) * 576) + k * 64 + row;
                    short8 bfr = *(const short8*)(wlds + chunk * 8);
                    acc[ct] = __builtin_amdgcn_mfma_f32_16x16x32_bf16(afr, bfr,
                                                                      acc[ct], 0, 0, 0);
                }
            }
        }
    };

    kpass(0);
    __syncthreads();
    // ---- stage s=1 weight half ----
    for (int c = tid; c < 2304; c += 256) {
        int k = c >> 8, row = (c >> 2) & 63, g2 = c & 3;
        uint4 v = *(const uint4*)(wb + (size_t)k * 4096 + row * 64 + (4 + g2) * 8);
        int dst = ((g2 ^ (row & 3)) * 576) + k * 64 + row;
        *(uint4*)(wlds + dst * 8) = v;
    }
    __syncthreads();
    kpass(1);

    // ---- epilogue: +bias, direct f4 stores, spread-atomic GN partials ----
#pragma unroll
    for (int ct = 0; ct < 4; ct++) {
        int co = ct * 16 + lm;
        float bias = b_dsc[co];
        f4 v;
        float sv = 0.f, sq = 0.f;
#pragma unroll
        for (int r = 0; r < 4; r++) {
            v[r] = acc[ct][r] + bias;
            sv += v[r]; sq += v[r] * v[r];
        }
        *(f4*)(outp + ((size_t)(b * C + co)) * HW + h * W + p0 + wid * 16 + qd * 4) = v;
        sv += __shfl_xor(sv, 16); sv += __shfl_xor(sv, 32);
        sq += __shfl_xor(sq, 16); sq += __shfl_xor(sq, 32);
        if (lane < 16) {
            red[((wid * 4 + ct) * 16 + lm) * 2]     = sv;
            red[((wid * 4 + ct) * 16 + lm) * 2 + 1] = sq;
        }
    }
    __syncthreads();
    if (tid < 128) {
        int co = tid >> 1, comp = tid & 1;
        int ct = co >> 4, lmr = co & 15;
        float s = 0.f;
#pragma unroll
        for (int w2 = 0; w2 < 4; w2++)
            s += red[((w2 * 4 + ct) * 16 + lmr) * 2 + comp];
        int sidx = (h >> 3) & 15;
        atomicAdd(&csum16[(sidx * 256 + b * 64 + co) * 2 + comp], s);
    }
}

// ---- K3: GN finalize (reduce csum16 in LDS) + apply + ReLU, XCD-aligned ----
__global__ __launch_bounds__(256) void k_norm(float* __restrict__ outp,
                                              const float* __restrict__ csum16,
                                              const float* __restrict__ g_gn,
                                              const float* __restrict__ b_gn) {
    __shared__ float lds[128];
    int bid = blockIdx.x;           // 4096 = xcd(8) x i(512)
    int xcd = bid & 7;
    int i   = bid >> 3;
    int bc  = i >> 1;
    int c2  = (xcd << 1) | (i & 1); // 8-row chunk index: h = c2*8.. -> same XCD
    int b = bc >> 6, co = bc & 63;
    int grp = co >> 2;
    int tid = threadIdx.x;

    if (tid < 128) {
        int s = tid >> 3, c = (tid >> 1) & 3, comp = tid & 1;
        lds[tid] = csum16[(s * 256 + b * 64 + grp * 4 + c) * 2 + comp];
    }
    __syncthreads();
#pragma unroll
    for (int st = 64; st >= 2; st >>= 1) {
        if (tid < st) lds[tid] += lds[tid + st];
        __syncthreads();
    }
    float S = lds[0], S2 = lds[1];
    float n = 4.f * HW;
    float mean = S / n;
    float var  = S2 / n - mean * mean;
    float rstd = rsqrtf(var + 1e-5f);
    float sc = rstd * g_gn[co];
    float sh = b_gn[co] - mean * sc;

    int idx = (bc * 16 + c2) * 256 + tid;
    float4* ptr = (float4*)outp;
    float4 vv = ptr[idx];
    vv.x = fmaxf(vv.x * sc + sh, 0.f);
    vv.y = fmaxf(vv.y * sc + sh, 0.f);
    vv.z = fmaxf(vv.z * sc + sh, 0.f);
    vv.w = fmaxf(vv.w * sc + sh, 0.f);
    ptr[idx] = vv;
}

extern "C" void kernel_launch(void* const* d_in, const int* in_sizes, int n_in,
                              void* d_out, int out_size, void* d_ws, size_t ws_size,
                              hipStream_t stream) {
    const float* x        = (const float*)d_in[0];
    const float* w_off    = (const float*)d_in[1];
    const float* b_off    = (const float*)d_in[2];
    const float* g_gn_off = (const float*)d_in[3];
    const float* b_gn_off = (const float*)d_in[4];
    const float* w_dsc    = (const float*)d_in[5];
    const float* b_dsc    = (const float*)d_in[6];
    const float* g_gn     = (const float*)d_in[7];
    const float* b_gn     = (const float*)d_in[8];
    float* out = (float*)d_out;
    float* ws  = (float*)d_ws;

    float*          offT   = ws + OFF_OFFT;
    unsigned short* xbp    = (unsigned short*)(ws + OFF_XB);
    unsigned short* wbp    = (unsigned short*)(ws + OFF_WB);
    unsigned short* wobp   = (unsigned short*)(ws + OFF_WOB);
    float*          csum16 = ws + OFF_CSUM;
    float*          osum16 = ws + OFF_OSUM;

    k_prep<<<2048 + 8 + 180 + 9, 256, 0, stream>>>(x, w_dsc, w_off, xbp, wbp,
                                                   wobp, csum16);
    k_offconv<<<2 * B * H, 256, 0, stream>>>(xbp, wobp, b_off, offT, osum16);
    k_main<<<2 * B * H, 256, 0, stream>>>(xbp, offT, osum16, g_gn_off, b_gn_off,
                                          wbp, b_dsc, out, csum16);
    k_norm<<<B * C * HW / 4 / 256, 256, 0, stream>>>(out, csum16, g_gn, b_gn);
}